// Round 10
// baseline (220.351 us; speedup 1.0000x reference)
//
#include <hip/hip_runtime.h>

#define BB 16384
#define KK 64
#define DD 128
#define SEG 256          // rows per covariance work-item (2x128-row stages)
#define MAXITEMS 256     // sum_k ceil(cnt_k/SEG) <= 64 + 63 = 127
#define NS 64            // reduce slabs per cluster (256 elems each)

typedef __attribute__((ext_vector_type(8))) short bf16x8;
typedef __attribute__((ext_vector_type(4))) float f32x4;

__device__ __forceinline__ unsigned int packbf2(float a, float b) {
    unsigned ua = __float_as_uint(a);
    unsigned ub = __float_as_uint(b);
    ua = (ua + 0x7FFFu + ((ua >> 16) & 1u)) >> 16;   // RNE f32->bf16
    ub = (ub + 0x7FFFu + ((ub >> 16) & 1u)) >> 16;
    return ua | (ub << 16);
}

// ---------------------------------------------------------------------------
// K1: tiled GEMM. Block = 64 rows x 64 clusters, K=128.
// dist = |x|^2 - 2 x.c + |c|^2 ; |x|^2 cancels in softmax AND argmin.
// Emits per-block cluster histogram bhist[b][k]; zeroes outscalars + emp.
// ---------------------------------------------------------------------------
__global__ __launch_bounds__(256) void k_rows(
    const float* __restrict__ x, const float* __restrict__ centers,
    float* __restrict__ log_resp, int* __restrict__ assign,
    int* __restrict__ bhist, float* __restrict__ outscalars,
    float* __restrict__ emp)
{
    __shared__ float xs[64][132];    // X tile, +4 pad
    __shared__ float ct[DD][66];     // centers transposed [d][k]
    __shared__ float cn2[KK];
    __shared__ int   lh[KK];

    const int tid = threadIdx.x;
    const int row0 = blockIdx.x * 64;

    if (blockIdx.x == 0 && tid < 2) outscalars[tid] = 0.f;
    if (tid < 32) emp[blockIdx.x * 32 + tid] = 0.f;   // 256*32 = 8192
    if (tid < KK) lh[tid] = 0;

    for (int g = tid; g < 64 * 32; g += 256) {
        int r = g >> 5, c4 = g & 31;
        float4 v = ((const float4*)(x + (size_t)(row0 + r) * DD))[c4];
        *(float4*)&xs[r][c4 * 4] = v;
    }
    for (int g = tid; g < KK * 32; g += 256) {
        int k = g >> 5, c4 = g & 31;
        float4 v = ((const float4*)(centers + (size_t)k * DD))[c4];
        ct[c4 * 4 + 0][k] = v.x;
        ct[c4 * 4 + 1][k] = v.y;
        ct[c4 * 4 + 2][k] = v.z;
        ct[c4 * 4 + 3][k] = v.w;
    }
    __syncthreads();
    if (tid < KK) {
        float s = 0.f;
        for (int d = 0; d < DD; ++d) { float c = ct[d][tid]; s = fmaf(c, c, s); }
        cn2[tid] = s;
    }
    __syncthreads();

    const int tr = tid >> 5;
    const int tc = tid & 31;
    const int k0 = tc * 2, k1 = k0 + 1;

    float acc0[8], acc1[8];
    #pragma unroll
    for (int i = 0; i < 8; ++i) { acc0[i] = 0.f; acc1[i] = 0.f; }

    for (int d = 0; d < DD; d += 4) {
        float2 b0 = *(const float2*)&ct[d + 0][k0];
        float2 b1 = *(const float2*)&ct[d + 1][k0];
        float2 b2 = *(const float2*)&ct[d + 2][k0];
        float2 b3 = *(const float2*)&ct[d + 3][k0];
        #pragma unroll
        for (int i = 0; i < 8; ++i) {
            float4 a = *(const float4*)&xs[tr * 8 + i][d];
            acc0[i] = fmaf(a.x, b0.x, acc0[i]);
            acc1[i] = fmaf(a.x, b0.y, acc1[i]);
            acc0[i] = fmaf(a.y, b1.x, acc0[i]);
            acc1[i] = fmaf(a.y, b1.y, acc1[i]);
            acc0[i] = fmaf(a.z, b2.x, acc0[i]);
            acc1[i] = fmaf(a.z, b2.y, acc1[i]);
            acc0[i] = fmaf(a.w, b3.x, acc0[i]);
            acc1[i] = fmaf(a.w, b3.y, acc1[i]);
        }
    }

    const float cn0 = 0.5f * cn2[k0], cn1 = 0.5f * cn2[k1];
    #pragma unroll
    for (int i = 0; i < 8; ++i) {
        int row = row0 + tr * 8 + i;
        float v0 = acc0[i] - cn0;
        float v1 = acc1[i] - cn1;
        float m; int idx;
        if (v1 > v0) { m = v1; idx = k1; } else { m = v0; idx = k0; }
        #pragma unroll
        for (int off = 1; off < 32; off <<= 1) {
            float ov = __shfl_xor(m, off);
            int   oi = __shfl_xor(idx, off);
            if (ov > m || (ov == m && oi < idx)) { m = ov; idx = oi; }
        }
        float s = expf(v0 - m) + expf(v1 - m);
        #pragma unroll
        for (int off = 1; off < 32; off <<= 1) s += __shfl_xor(s, off);
        float ls = logf(s);
        float lr0 = fmaxf(v0 - m - ls, -18.4206807f);  // log(1e-8)
        float lr1 = fmaxf(v1 - m - ls, -18.4206807f);
        *(float2*)&log_resp[(size_t)row * KK + k0] = make_float2(lr0, lr1);
        if (tc == 0) {
            assign[row] = idx;
            atomicAdd(&lh[idx], 1);
        }
    }
    __syncthreads();
    if (tid < KK) bhist[blockIdx.x * KK + tid] = lh[tid];   // coalesced 256B
}

// ---------------------------------------------------------------------------
// K2 (256 blocks): parallel counting-sort scatter (R8). Block 0 emits items
// (SEG=256 now) / ist / ien / itemcnt / cw.
// ---------------------------------------------------------------------------
__global__ __launch_bounds__(256) void k_scat(
    const int* __restrict__ assign, const int* __restrict__ bhist,
    int* __restrict__ sorted, float* __restrict__ cw,
    int4* __restrict__ items, int* __restrict__ item_count,
    int* __restrict__ ist, int* __restrict__ ien)
{
    __shared__ int ph_tot[4][KK], ph_pre[4][KK];
    __shared__ int cnt_s[KK], pre_s[KK], base_s[KK], cur_s[KK];

    const int tid = threadIdx.x;
    const int b = blockIdx.x;
    const int t = tid & 63, q = tid >> 6;

    int tot = 0, pre = 0;
    const int bb0 = q * 64;
    for (int bb = bb0; bb < bb0 + 64; ++bb) {
        int v = bhist[bb * KK + t];          // lanes consecutive: coalesced
        tot += v;
        if (bb < b) pre += v;
    }
    ph_tot[q][t] = tot; ph_pre[q][t] = pre;
    __syncthreads();

    if (tid < KK) {
        cnt_s[tid] = ph_tot[0][tid] + ph_tot[1][tid] + ph_tot[2][tid] + ph_tot[3][tid];
        pre_s[tid] = ph_pre[0][tid] + ph_pre[1][tid] + ph_pre[2][tid] + ph_pre[3][tid];
        cur_s[tid] = 0;
    }
    __syncthreads();
    if (tid == 0) {
        int base = 0;
        for (int k = 0; k < KK; ++k) { base_s[k] = base; base += cnt_s[k]; }
    }
    __syncthreads();

    if (tid < 64) {
        int r = b * 64 + tid;
        int a = assign[r];
        int p = base_s[a] + pre_s[a] + atomicAdd(&cur_s[a], 1);
        sorted[p] = r;                       // intra-cluster order: don't care
    }

    if (b == 0) {
        if (tid < KK) cw[tid] = (float)cnt_s[tid];
        if (tid == 0) {
            int ic = 0;
            for (int k = 0; k < KK; ++k) {
                ist[k] = ic;
                int c = cnt_s[k];
                for (int s = 0; s < c; s += SEG) {
                    int4 it; it.x = k; it.y = base_s[k] + s;
                    it.z = min(SEG, c - s); it.w = 0;
                    items[ic++] = it;
                }
                ien[k] = ic;
            }
            *item_count = ic;
        }
    }
}

// ---------------------------------------------------------------------------
// K3 (MFMA): one block per item (<=256 rows, staged as two 128-row halves
// into the same accumulators). XT[d][row-pair u32] bf16, Sxx = X^T X via
// mfma_f32_16x16x32_bf16 (symmetric output: transpose-robust). Column sums
// in f32 from identical bf16 data -> emp atomics. SEG=256 halves the partial
// count vs R9 -> halves k_redfinal's read volume.
// ---------------------------------------------------------------------------
__global__ __launch_bounds__(256) void k_seg(
    const float* __restrict__ x, const int* __restrict__ sorted,
    const int4* __restrict__ items, const int* __restrict__ item_count,
    float* __restrict__ part, float* __restrict__ emp)
{
    if ((int)blockIdx.x >= *item_count) return;
    int4 it = items[blockIdx.x];
    const int k = it.x, gstart = it.y, len = it.z;   // len <= 256

    __shared__ int rows_s[128];
    __shared__ unsigned int XT[DD][68];   // XT[d][j] = bf16 pair rows (2j,2j+1)

    const int tid = threadIdx.x;
    const int w = tid >> 6, lane = tid & 63;
    const int c4 = lane & 15, q = lane >> 4;

    f32x4 acc[2][8];
    #pragma unroll
    for (int h = 0; h < 2; ++h)
        #pragma unroll
        for (int nt = 0; nt < 8; ++nt)
            acc[h][nt] = (f32x4){0.f, 0.f, 0.f, 0.f};
    float colsum = 0.f;

    for (int half = 0; half < 2; ++half) {
        const int hoff = half * 128;
        const int hlen = min(128, len - hoff);     // uniform across block
        if (hlen <= 0) break;

        __syncthreads();   // WAR: prev half's XT/rows_s reads complete
        if (tid < hlen) rows_s[tid] = sorted[gstart + hoff + tid];
        __syncthreads();

        // stage: wave w owns dims [w*32, w*32+32); lane owns row pair
        {
            const int r0 = 2 * lane, r1 = 2 * lane + 1;
            const int d0 = w * 32;
            const float* p0 = x + (size_t)rows_s[r0 < hlen ? r0 : 0] * DD + d0;
            const float* p1 = x + (size_t)rows_s[r1 < hlen ? r1 : 0] * DD + d0;
            #pragma unroll
            for (int i = 0; i < 8; ++i) {
                float4 a = make_float4(0.f, 0.f, 0.f, 0.f);
                float4 b = make_float4(0.f, 0.f, 0.f, 0.f);
                if (r0 < hlen) a = *(const float4*)(p0 + 4 * i);
                if (r1 < hlen) b = *(const float4*)(p1 + 4 * i);
                XT[d0 + 4 * i + 0][lane] = packbf2(a.x, b.x);
                XT[d0 + 4 * i + 1][lane] = packbf2(a.y, b.y);
                XT[d0 + 4 * i + 2][lane] = packbf2(a.z, b.z);
                XT[d0 + 4 * i + 3][lane] = packbf2(a.w, b.w);
            }
        }
        __syncthreads();

        // column sums (f32 from the bf16 data): thread d < 128
        if (tid < DD) {
            float s = 0.f;
            #pragma unroll
            for (int j4 = 0; j4 < 16; ++j4) {
                uint4 v = *(const uint4*)&XT[tid][j4 * 4];
                s += __uint_as_float(v.x << 16) + __uint_as_float(v.x & 0xFFFF0000u);
                s += __uint_as_float(v.y << 16) + __uint_as_float(v.y & 0xFFFF0000u);
                s += __uint_as_float(v.z << 16) + __uint_as_float(v.z & 0xFFFF0000u);
                s += __uint_as_float(v.w << 16) + __uint_as_float(v.w & 0xFFFF0000u);
            }
            colsum += s;
        }

        // MFMA: wave w owns m-tiles {2w, 2w+1} x n-tiles 0..7
        #pragma unroll
        for (int c = 0; c < 4; ++c) {          // K chunks of 32 rows
            const int ku = c * 16 + q * 4;     // u32 index: k0 = c*32 + q*8
            bf16x8 a0 = *(const bf16x8*)&XT[(2 * w + 0) * 16 + c4][ku];
            bf16x8 a1 = *(const bf16x8*)&XT[(2 * w + 1) * 16 + c4][ku];
            #pragma unroll
            for (int nt = 0; nt < 8; ++nt) {
                bf16x8 b = *(const bf16x8*)&XT[nt * 16 + c4][ku];
                acc[0][nt] = __builtin_amdgcn_mfma_f32_16x16x32_bf16(a0, b, acc[0][nt], 0, 0, 0);
                acc[1][nt] = __builtin_amdgcn_mfma_f32_16x16x32_bf16(a1, b, acc[1][nt], 0, 0, 0);
            }
        }
    }

    if (tid < DD) atomicAdd(&emp[k * DD + tid], colsum);

    // C/D layout: col = lane&15, row = quad*4 + reg  [m89/m91 verified]
    float* pb = part + (size_t)blockIdx.x * (DD * DD);
    #pragma unroll
    for (int h = 0; h < 2; ++h) {
        const int m0 = (2 * w + h) * 16 + q * 4;
        #pragma unroll
        for (int nt = 0; nt < 8; ++nt) {
            const int n = nt * 16 + c4;
            pb[(m0 + 0) * DD + n] = acc[h][nt].x;
            pb[(m0 + 1) * DD + n] = acc[h][nt].y;
            pb[(m0 + 2) * DD + n] = acc[h][nt].z;
            pb[(m0 + 3) * DD + n] = acc[h][nt].w;
        }
    }
}

// ---------------------------------------------------------------------------
// K4: grid = KK x NS(=64) slabs of 256 elems. One elem per thread, items
// reduced depth-wise with even/odd accumulator split (MLP); coalesced 1KB
// block reads per item. Dominant cluster now gets 64 reducer blocks instead
// of 8 (R9's hidden 10us+ tail: 8 blocks x 1MB serial gather).
// ---------------------------------------------------------------------------
__global__ __launch_bounds__(256) void k_redfinal(
    const float* __restrict__ part, const float* __restrict__ emp,
    const float* __restrict__ cw, const float* __restrict__ centers,
    const int* __restrict__ ist, const int* __restrict__ ien,
    float* __restrict__ outscalars)
{
    const int k = blockIdx.x >> 6;
    const int p = blockIdx.x & (NS - 1);
    const int i0 = ist[k], i1 = ien[k];
    const int tid = threadIdx.x;
    const int w = tid >> 6, lane = tid & 63;
    const float wgt = cw[k];
    const float inv = 1.0f / (wgt + 1e-7f);

    __shared__ float mu_s[DD], emp_s[DD];
    if (tid < DD) {
        float e = emp[k * DD + tid];
        emp_s[tid] = e;
        mu_s[tid] = e * inv;
    }
    __syncthreads();

    const int gel = p * 256 + tid;        // element in [0, 16384)
    float s0 = 0.f, s1 = 0.f;
    int it = i0;
    for (; it + 1 < i1; it += 2) {
        s0 += part[(size_t)it * (DD * DD) + gel];
        s1 += part[(size_t)(it + 1) * (DD * DD) + gel];
    }
    if (it < i1) s0 += part[(size_t)it * (DD * DD) + gel];
    const float sx = s0 + s1;

    const int d = gel >> 7, e = gel & 127;
    float ctv = sx - mu_s[d] * emp_s[e] - emp_s[d] * mu_s[e]
              + wgt * mu_s[d] * mu_s[e];
    float v = ctv * inv;
    float ds = 0.f, os = 0.f, mm = 0.f;
    if (d == e) { float t = v - 1.f; ds = t * t; }
    else        { os = v * v; }
    if (p == 0 && tid < DD) {
        float t = mu_s[tid] - centers[k * DD + tid];
        mm = t * t;
    }

    #pragma unroll
    for (int off = 32; off > 0; off >>= 1) {
        ds += __shfl_down(ds, off);
        os += __shfl_down(os, off);
        mm += __shfl_down(mm, off);
    }
    __shared__ float rds[4], ros[4], rmm[4];
    if (lane == 0) { rds[w] = ds; ros[w] = os; rmm[w] = mm; }
    __syncthreads();
    if (tid == 0) {
        float DS = rds[0] + rds[1] + rds[2] + rds[3];
        float OS = ros[0] + ros[1] + ros[2] + ros[3];
        float MM = rmm[0] + rmm[1] + rmm[2] + rmm[3];
        const float bd = (float)BB * (float)DD;
        atomicAdd(&outscalars[0], wgt * MM / bd);
        atomicAdd(&outscalars[1], wgt * DS / bd + wgt * OS / (bd * (float)(DD - 1)));
    }
}

// ---------------------------------------------------------------------------
extern "C" void kernel_launch(void* const* d_in, const int* in_sizes, int n_in,
                              void* d_out, int out_size, void* d_ws, size_t ws_size,
                              hipStream_t stream) {
    const float* x = (const float*)d_in[0];
    const float* centers = (const float*)d_in[1];
    float* out = (float*)d_out;
    float* outscalars = out + (size_t)BB * KK;

    char* ws = (char*)d_ws;
    size_t off = 0;
    float* part    = (float*)(ws + off); off += (size_t)MAXITEMS * DD * DD * 4; // 16 MB
    float* emp     = (float*)(ws + off); off += KK * DD * 4;                    // 32 KB
    int*   sorted  = (int*)  (ws + off); off += BB * 4;                         // 64 KB
    int*   assign  = (int*)  (ws + off); off += BB * 4;                         // 64 KB
    int*   bhist   = (int*)  (ws + off); off += 256 * KK * 4;                   // 64 KB
    int4*  items   = (int4*) (ws + off); off += MAXITEMS * 16;
    float* cw      = (float*)(ws + off); off += 256;
    int*   itemcnt = (int*)  (ws + off); off += 256;
    int*   ist     = (int*)  (ws + off); off += 256;
    int*   ien     = (int*)  (ws + off); off += 256;

    k_rows    <<<256, 256, 0, stream>>>(x, centers, out, assign, bhist,
                                        outscalars, emp);
    k_scat    <<<256, 256, 0, stream>>>(assign, bhist, sorted, cw, items,
                                        itemcnt, ist, ien);
    k_seg     <<<128, 256, 0, stream>>>(x, sorted, items, itemcnt, part, emp);
    k_redfinal<<<KK * NS, 256, 0, stream>>>(part, emp, cw, centers, ist, ien,
                                            outscalars);
}

// Round 11
// 126.463 us; speedup vs baseline: 1.7424x; 1.7424x over previous
//
#include <hip/hip_runtime.h>

#define BB 16384
#define KK 64
#define DD 128
#define SEG 256          // rows per covariance work-item (2x128-row stages)
#define MAXITEMS 128     // sum_k ceil(cnt_k/SEG) <= 64 + 63 = 127
#define NRB 4            // reduce slabs per cluster
#define RSLAB 4096       // elements per reduce slab
#define RBLKS (KK * NRB) // 256 reducer blocks

typedef __attribute__((ext_vector_type(8))) short bf16x8;
typedef __attribute__((ext_vector_type(4))) float f32x4;

__device__ __forceinline__ unsigned int packbf2(float a, float b) {
    unsigned ua = __float_as_uint(a);
    unsigned ub = __float_as_uint(b);
    ua = (ua + 0x7FFFu + ((ua >> 16) & 1u)) >> 16;   // RNE f32->bf16
    ub = (ub + 0x7FFFu + ((ub >> 16) & 1u)) >> 16;
    return ua | (ub << 16);
}

// ---------------------------------------------------------------------------
// K1: tiled GEMM. Block = 64 rows x 64 clusters, K=128.
// dist = |x|^2 - 2 x.c + |c|^2 ; |x|^2 cancels in softmax AND argmin.
// Emits per-block cluster histogram bhist[b][k]; zeroes the done-counter.
// ---------------------------------------------------------------------------
__global__ __launch_bounds__(256) void k_rows(
    const float* __restrict__ x, const float* __restrict__ centers,
    float* __restrict__ log_resp, int* __restrict__ assign,
    int* __restrict__ bhist, int* __restrict__ counter)
{
    __shared__ float xs[64][132];    // X tile, +4 pad
    __shared__ float ct[DD][66];     // centers transposed [d][k]
    __shared__ float cn2[KK];
    __shared__ int   lh[KK];

    const int tid = threadIdx.x;
    const int row0 = blockIdx.x * 64;

    if (blockIdx.x == 0 && tid == 0) *counter = 0;
    if (tid < KK) lh[tid] = 0;

    for (int g = tid; g < 64 * 32; g += 256) {
        int r = g >> 5, c4 = g & 31;
        float4 v = ((const float4*)(x + (size_t)(row0 + r) * DD))[c4];
        *(float4*)&xs[r][c4 * 4] = v;
    }
    for (int g = tid; g < KK * 32; g += 256) {
        int k = g >> 5, c4 = g & 31;
        float4 v = ((const float4*)(centers + (size_t)k * DD))[c4];
        ct[c4 * 4 + 0][k] = v.x;
        ct[c4 * 4 + 1][k] = v.y;
        ct[c4 * 4 + 2][k] = v.z;
        ct[c4 * 4 + 3][k] = v.w;
    }
    __syncthreads();
    if (tid < KK) {
        float s = 0.f;
        for (int d = 0; d < DD; ++d) { float c = ct[d][tid]; s = fmaf(c, c, s); }
        cn2[tid] = s;
    }
    __syncthreads();

    const int tr = tid >> 5;
    const int tc = tid & 31;
    const int k0 = tc * 2, k1 = k0 + 1;

    float acc0[8], acc1[8];
    #pragma unroll
    for (int i = 0; i < 8; ++i) { acc0[i] = 0.f; acc1[i] = 0.f; }

    for (int d = 0; d < DD; d += 4) {
        float2 b0 = *(const float2*)&ct[d + 0][k0];
        float2 b1 = *(const float2*)&ct[d + 1][k0];
        float2 b2 = *(const float2*)&ct[d + 2][k0];
        float2 b3 = *(const float2*)&ct[d + 3][k0];
        #pragma unroll
        for (int i = 0; i < 8; ++i) {
            float4 a = *(const float4*)&xs[tr * 8 + i][d];
            acc0[i] = fmaf(a.x, b0.x, acc0[i]);
            acc1[i] = fmaf(a.x, b0.y, acc1[i]);
            acc0[i] = fmaf(a.y, b1.x, acc0[i]);
            acc1[i] = fmaf(a.y, b1.y, acc1[i]);
            acc0[i] = fmaf(a.z, b2.x, acc0[i]);
            acc1[i] = fmaf(a.z, b2.y, acc1[i]);
            acc0[i] = fmaf(a.w, b3.x, acc0[i]);
            acc1[i] = fmaf(a.w, b3.y, acc1[i]);
        }
    }

    const float cn0 = 0.5f * cn2[k0], cn1 = 0.5f * cn2[k1];
    #pragma unroll
    for (int i = 0; i < 8; ++i) {
        int row = row0 + tr * 8 + i;
        float v0 = acc0[i] - cn0;
        float v1 = acc1[i] - cn1;
        float m; int idx;
        if (v1 > v0) { m = v1; idx = k1; } else { m = v0; idx = k0; }
        #pragma unroll
        for (int off = 1; off < 32; off <<= 1) {
            float ov = __shfl_xor(m, off);
            int   oi = __shfl_xor(idx, off);
            if (ov > m || (ov == m && oi < idx)) { m = ov; idx = oi; }
        }
        float s = expf(v0 - m) + expf(v1 - m);
        #pragma unroll
        for (int off = 1; off < 32; off <<= 1) s += __shfl_xor(s, off);
        float ls = logf(s);
        float lr0 = fmaxf(v0 - m - ls, -18.4206807f);  // log(1e-8)
        float lr1 = fmaxf(v1 - m - ls, -18.4206807f);
        *(float2*)&log_resp[(size_t)row * KK + k0] = make_float2(lr0, lr1);
        if (tc == 0) {
            assign[row] = idx;
            atomicAdd(&lh[idx], 1);
        }
    }
    __syncthreads();
    if (tid < KK) bhist[blockIdx.x * KK + tid] = lh[tid];   // coalesced 256B
}

// ---------------------------------------------------------------------------
// K2 (256 blocks): parallel counting-sort scatter (R8). Block 0 emits items
// (SEG=256) / ist / ien / itemcnt / cw.
// ---------------------------------------------------------------------------
__global__ __launch_bounds__(256) void k_scat(
    const int* __restrict__ assign, const int* __restrict__ bhist,
    int* __restrict__ sorted, float* __restrict__ cw,
    int4* __restrict__ items, int* __restrict__ item_count,
    int* __restrict__ ist, int* __restrict__ ien)
{
    __shared__ int ph_tot[4][KK], ph_pre[4][KK];
    __shared__ int cnt_s[KK], pre_s[KK], base_s[KK], cur_s[KK];

    const int tid = threadIdx.x;
    const int b = blockIdx.x;
    const int t = tid & 63, q = tid >> 6;

    int tot = 0, pre = 0;
    const int bb0 = q * 64;
    for (int bb = bb0; bb < bb0 + 64; ++bb) {
        int v = bhist[bb * KK + t];          // lanes consecutive: coalesced
        tot += v;
        if (bb < b) pre += v;
    }
    ph_tot[q][t] = tot; ph_pre[q][t] = pre;
    __syncthreads();

    if (tid < KK) {
        cnt_s[tid] = ph_tot[0][tid] + ph_tot[1][tid] + ph_tot[2][tid] + ph_tot[3][tid];
        pre_s[tid] = ph_pre[0][tid] + ph_pre[1][tid] + ph_pre[2][tid] + ph_pre[3][tid];
        cur_s[tid] = 0;
    }
    __syncthreads();
    if (tid == 0) {
        int base = 0;
        for (int k = 0; k < KK; ++k) { base_s[k] = base; base += cnt_s[k]; }
    }
    __syncthreads();

    if (tid < 64) {
        int r = b * 64 + tid;
        int a = assign[r];
        int p = base_s[a] + pre_s[a] + atomicAdd(&cur_s[a], 1);
        sorted[p] = r;                       // intra-cluster order: don't care
    }

    if (b == 0) {
        if (tid < KK) cw[tid] = (float)cnt_s[tid];
        if (tid == 0) {
            int ic = 0;
            for (int k = 0; k < KK; ++k) {
                ist[k] = ic;
                int c = cnt_s[k];
                for (int s = 0; s < c; s += SEG) {
                    int4 it; it.x = k; it.y = base_s[k] + s;
                    it.z = min(SEG, c - s); it.w = 0;
                    items[ic++] = it;
                }
                ien[k] = ic;
            }
            *item_count = ic;
        }
    }
}

// ---------------------------------------------------------------------------
// K3 (MFMA): one block per item (<=256 rows, two 128-row stages into the same
// accumulators). Sxx = X^T X via mfma_f32_16x16x32_bf16. Column sums now go
// NON-atomically to emp_part[item][d] (R10 lesson: same-line atomics ~13ns
// each, serialized; k_redfinal sums emp_part instead).
// ---------------------------------------------------------------------------
__global__ __launch_bounds__(256) void k_seg(
    const float* __restrict__ x, const int* __restrict__ sorted,
    const int4* __restrict__ items, const int* __restrict__ item_count,
    float* __restrict__ part, float* __restrict__ emp_part)
{
    if ((int)blockIdx.x >= *item_count) return;
    int4 it = items[blockIdx.x];
    const int gstart = it.y, len = it.z;   // len <= 256

    __shared__ int rows_s[128];
    __shared__ unsigned int XT[DD][68];   // XT[d][j] = bf16 pair rows (2j,2j+1)

    const int tid = threadIdx.x;
    const int w = tid >> 6, lane = tid & 63;
    const int c4 = lane & 15, q = lane >> 4;

    f32x4 acc[2][8];
    #pragma unroll
    for (int h = 0; h < 2; ++h)
        #pragma unroll
        for (int nt = 0; nt < 8; ++nt)
            acc[h][nt] = (f32x4){0.f, 0.f, 0.f, 0.f};
    float colsum = 0.f;

    for (int half = 0; half < 2; ++half) {
        const int hoff = half * 128;
        const int hlen = min(128, len - hoff);     // uniform across block
        if (hlen <= 0) break;

        __syncthreads();   // WAR: prev half's XT/rows_s reads complete
        if (tid < hlen) rows_s[tid] = sorted[gstart + hoff + tid];
        __syncthreads();

        // stage: wave w owns dims [w*32, w*32+32); lane owns row pair
        {
            const int r0 = 2 * lane, r1 = 2 * lane + 1;
            const int d0 = w * 32;
            const float* p0 = x + (size_t)rows_s[r0 < hlen ? r0 : 0] * DD + d0;
            const float* p1 = x + (size_t)rows_s[r1 < hlen ? r1 : 0] * DD + d0;
            #pragma unroll
            for (int i = 0; i < 8; ++i) {
                float4 a = make_float4(0.f, 0.f, 0.f, 0.f);
                float4 b = make_float4(0.f, 0.f, 0.f, 0.f);
                if (r0 < hlen) a = *(const float4*)(p0 + 4 * i);
                if (r1 < hlen) b = *(const float4*)(p1 + 4 * i);
                XT[d0 + 4 * i + 0][lane] = packbf2(a.x, b.x);
                XT[d0 + 4 * i + 1][lane] = packbf2(a.y, b.y);
                XT[d0 + 4 * i + 2][lane] = packbf2(a.z, b.z);
                XT[d0 + 4 * i + 3][lane] = packbf2(a.w, b.w);
            }
        }
        __syncthreads();

        // column sums (f32 from the bf16 data): thread d < 128
        if (tid < DD) {
            float s = 0.f;
            #pragma unroll
            for (int j4 = 0; j4 < 16; ++j4) {
                uint4 v = *(const uint4*)&XT[tid][j4 * 4];
                s += __uint_as_float(v.x << 16) + __uint_as_float(v.x & 0xFFFF0000u);
                s += __uint_as_float(v.y << 16) + __uint_as_float(v.y & 0xFFFF0000u);
                s += __uint_as_float(v.z << 16) + __uint_as_float(v.z & 0xFFFF0000u);
                s += __uint_as_float(v.w << 16) + __uint_as_float(v.w & 0xFFFF0000u);
            }
            colsum += s;
        }

        // MFMA: wave w owns m-tiles {2w, 2w+1} x n-tiles 0..7
        #pragma unroll
        for (int c = 0; c < 4; ++c) {          // K chunks of 32 rows
            const int ku = c * 16 + q * 4;     // u32 index: k0 = c*32 + q*8
            bf16x8 a0 = *(const bf16x8*)&XT[(2 * w + 0) * 16 + c4][ku];
            bf16x8 a1 = *(const bf16x8*)&XT[(2 * w + 1) * 16 + c4][ku];
            #pragma unroll
            for (int nt = 0; nt < 8; ++nt) {
                bf16x8 b = *(const bf16x8*)&XT[nt * 16 + c4][ku];
                acc[0][nt] = __builtin_amdgcn_mfma_f32_16x16x32_bf16(a0, b, acc[0][nt], 0, 0, 0);
                acc[1][nt] = __builtin_amdgcn_mfma_f32_16x16x32_bf16(a1, b, acc[1][nt], 0, 0, 0);
            }
        }
    }

    if (tid < DD) emp_part[blockIdx.x * DD + tid] = colsum;   // non-atomic

    // C/D layout: col = lane&15, row = quad*4 + reg  [m89/m91 verified]
    float* pb = part + (size_t)blockIdx.x * (DD * DD);
    #pragma unroll
    for (int h = 0; h < 2; ++h) {
        const int m0 = (2 * w + h) * 16 + q * 4;
        #pragma unroll
        for (int nt = 0; nt < 8; ++nt) {
            const int n = nt * 16 + c4;
            pb[(m0 + 0) * DD + n] = acc[h][nt].x;
            pb[(m0 + 1) * DD + n] = acc[h][nt].y;
            pb[(m0 + 2) * DD + n] = acc[h][nt].z;
            pb[(m0 + 3) * DD + n] = acc[h][nt].w;
        }
    }
}

// ---------------------------------------------------------------------------
// K4: grid = KK x NRB(=4) slabs of 4096 elems. Wave-streaming reduce of item
// partials (R6-verified: 16KB contiguous per wave per item, 16 acc chains),
// emp summed from emp_part (4 MLP chains), centered covariance, then
// NON-atomic spart[block] + counter; last block sums 256 partials and writes
// the two output scalars directly. (R10 lesson: 8192 same-line atomics were
// 107us; this has 256 counter atomics ~3us.)
// ---------------------------------------------------------------------------
__global__ __launch_bounds__(256) void k_redfinal(
    const float* __restrict__ part, const float* __restrict__ emp_part,
    const float* __restrict__ cw, const float* __restrict__ centers,
    const int* __restrict__ ist, const int* __restrict__ ien,
    float2* __restrict__ spart, int* __restrict__ counter,
    float* __restrict__ outscalars)
{
    const int k = blockIdx.x >> 2;
    const int p = blockIdx.x & 3;
    const int i0 = ist[k], i1 = ien[k];
    const int tid = threadIdx.x;
    const int w = tid >> 6, lane = tid & 63;
    const float wgt = cw[k];
    const float inv = 1.0f / (wgt + 1e-7f);

    __shared__ float mu_s[DD], emp_s[DD];
    __shared__ float emp2[2][DD];
    __shared__ float red[4][RSLAB];      // 64 KB

    // emp = sum over items of emp_part (2 thread-groups x 2 chains = MLP 4)
    {
        const int dh = tid & 127, hf = tid >> 7;
        float e0 = 0.f, e1 = 0.f;
        int it = i0 + hf;
        for (; it + 2 < i1; it += 4) {
            e0 += emp_part[it * DD + dh];
            e1 += emp_part[(it + 2) * DD + dh];
        }
        if (it < i1) e0 += emp_part[it * DD + dh];
        emp2[hf][dh] = e0 + e1;
    }
    __syncthreads();
    if (tid < DD) {
        float e = emp2[0][tid] + emp2[1][tid];
        emp_s[tid] = e;
        mu_s[tid] = e * inv;
    }

    float4 acc[16];
    #pragma unroll
    for (int c = 0; c < 16; ++c) acc[c] = make_float4(0.f, 0.f, 0.f, 0.f);

    const int base = p * RSLAB;
    for (int it = i0 + w; it < i1; it += 4) {
        const float* pb = part + (size_t)it * (DD * DD) + base;
        #pragma unroll
        for (int c = 0; c < 16; ++c) {
            float4 v = *(const float4*)&pb[c * 256 + lane * 4];
            acc[c].x += v.x; acc[c].y += v.y; acc[c].z += v.z; acc[c].w += v.w;
        }
    }
    #pragma unroll
    for (int c = 0; c < 16; ++c)
        *(float4*)&red[w][c * 256 + lane * 4] = acc[c];
    __syncthreads();   // also orders mu_s/emp_s writes

    float ds = 0.f, os = 0.f, mm = 0.f;
    #pragma unroll
    for (int jj = 0; jj < 16; ++jj) {
        int el = jj * 256 + tid;               // stride-1 across lanes
        float sx = red[0][el] + red[1][el] + red[2][el] + red[3][el];
        int gel = base + el;
        int d = gel >> 7, e = gel & 127;
        float ctv = sx - mu_s[d] * emp_s[e] - emp_s[d] * mu_s[e]
                  + wgt * mu_s[d] * mu_s[e];
        float v = ctv * inv;
        if (d == e) { float t = v - 1.f; ds += t * t; }
        else        { os += v * v; }
    }
    if (p == 0 && tid < DD) {
        float t = mu_s[tid] - centers[k * DD + tid];
        mm = t * t;
    }

    #pragma unroll
    for (int off = 32; off > 0; off >>= 1) {
        ds += __shfl_down(ds, off);
        os += __shfl_down(os, off);
        mm += __shfl_down(mm, off);
    }
    __shared__ float rds[4], ros[4], rmm[4];
    __shared__ int is_last;
    if (lane == 0) { rds[w] = ds; ros[w] = os; rmm[w] = mm; }
    __syncthreads();
    if (tid == 0) {
        float DS = rds[0] + rds[1] + rds[2] + rds[3];
        float OS = ros[0] + ros[1] + ros[2] + ros[3];
        float MM = rmm[0] + rmm[1] + rmm[2] + rmm[3];
        const float bd = (float)BB * (float)DD;
        float2 mine;
        mine.x = wgt * MM / bd;
        mine.y = wgt * DS / bd + wgt * OS / (bd * (float)(DD - 1));
        spart[blockIdx.x] = mine;
        __threadfence();                       // release partial
        int old = atomicAdd(counter, 1);
        is_last = (old == RBLKS - 1);
    }
    __syncthreads();
    if (is_last) {
        __threadfence();                       // acquire all partials
        float2 v = (tid < RBLKS) ? spart[tid] : make_float2(0.f, 0.f);
        float a = v.x, b = v.y;
        #pragma unroll
        for (int off = 32; off > 0; off >>= 1) {
            a += __shfl_down(a, off);
            b += __shfl_down(b, off);
        }
        __shared__ float ra[4], rb[4];
        if (lane == 0) { ra[w] = a; rb[w] = b; }
        __syncthreads();
        if (tid == 0) {
            outscalars[0] = ra[0] + ra[1] + ra[2] + ra[3];
            outscalars[1] = rb[0] + rb[1] + rb[2] + rb[3];
        }
    }
}

// ---------------------------------------------------------------------------
extern "C" void kernel_launch(void* const* d_in, const int* in_sizes, int n_in,
                              void* d_out, int out_size, void* d_ws, size_t ws_size,
                              hipStream_t stream) {
    const float* x = (const float*)d_in[0];
    const float* centers = (const float*)d_in[1];
    float* out = (float*)d_out;
    float* outscalars = out + (size_t)BB * KK;

    char* ws = (char*)d_ws;
    size_t off = 0;
    float*  part     = (float*)(ws + off); off += (size_t)MAXITEMS * DD * DD * 4; // 8 MB
    float*  emp_part = (float*)(ws + off); off += MAXITEMS * DD * 4;              // 64 KB
    int*    sorted   = (int*)  (ws + off); off += BB * 4;                         // 64 KB
    int*    assign   = (int*)  (ws + off); off += BB * 4;                         // 64 KB
    int*    bhist    = (int*)  (ws + off); off += 256 * KK * 4;                   // 64 KB
    int4*   items    = (int4*) (ws + off); off += 256 * 16;                       // 4 KB
    float*  cw       = (float*)(ws + off); off += 256;
    int*    itemcnt  = (int*)  (ws + off); off += 256;
    int*    ist      = (int*)  (ws + off); off += 256;
    int*    ien      = (int*)  (ws + off); off += 256;
    float2* spart    = (float2*)(ws + off); off += RBLKS * 8;                     // 2 KB
    int*    counter  = (int*)  (ws + off); off += 256;

    k_rows    <<<256, 256, 0, stream>>>(x, centers, out, assign, bhist, counter);
    k_scat    <<<256, 256, 0, stream>>>(assign, bhist, sorted, cw, items,
                                        itemcnt, ist, ien);
    k_seg     <<<MAXITEMS, 256, 0, stream>>>(x, sorted, items, itemcnt,
                                             part, emp_part);
    k_redfinal<<<RBLKS, 256, 0, stream>>>(part, emp_part, cw, centers, ist, ien,
                                          spart, counter, outscalars);
}